// Round 1
// baseline (1138.646 us; speedup 1.0000x reference)
//
#include <hip/hip_runtime.h>
#include <math.h>

#define Bsz 2
#define Ssz 4096
#define Esz 768
#define Hh 12
#define HDd 64
#define Ww 256
#define NBAND 513   // 2*W+1

// ======================= QKV GEMM =======================
// C = relu(A @ W + b) * scale, written head-major [B*H][S][HD]
#define BM 128
#define BN 128
#define BK 16
#define LDA_ (BM + 4)
#define LDB_ (BN + 4)

__global__ __launch_bounds__(256) void qkv_gemm(
    const float* __restrict__ A,
    const float* __restrict__ W0, const float* __restrict__ b0,
    const float* __restrict__ W1, const float* __restrict__ b1,
    const float* __restrict__ W2, const float* __restrict__ b2,
    float* __restrict__ ws)
{
    const int z = blockIdx.z;
    const float* Wm   = (z == 0) ? W0 : (z == 1) ? W1 : W2;
    const float* bias = (z == 0) ? b0 : (z == 1) ? b1 : b2;
    float* dst = ws + (size_t)z * (size_t)Bsz * Hh * Ssz * HDd;
    const float scale = (z == 0) ? 0.125f : 1.0f;   // q: relu(x)/sqrt(64)

    __shared__ float As[BK][LDA_];
    __shared__ float Bs[BK][LDB_];

    const int tid = threadIdx.x;
    const int tx = tid & 15;
    const int ty = tid >> 4;
    const int row0 = blockIdx.y * BM;
    const int col0 = blockIdx.x * BN;

    float acc[8][8];
    #pragma unroll
    for (int i = 0; i < 8; ++i)
        #pragma unroll
        for (int j = 0; j < 8; ++j) acc[i][j] = 0.f;

    const int lr = tid >> 1;          // A: row within tile, 0..127
    const int lk = (tid & 1) * 8;     // A: k offset, 0 or 8
    const int bk_r = tid >> 4;        // B: k row, 0..15
    const int bc = (tid & 15) * 8;    // B: col offset

    for (int k0 = 0; k0 < Esz; k0 += BK) {
        {
            const float* src = A + (size_t)(row0 + lr) * Esz + k0 + lk;
            float4 v0 = ((const float4*)src)[0];
            float4 v1 = ((const float4*)src)[1];
            As[lk+0][lr] = v0.x; As[lk+1][lr] = v0.y; As[lk+2][lr] = v0.z; As[lk+3][lr] = v0.w;
            As[lk+4][lr] = v1.x; As[lk+5][lr] = v1.y; As[lk+6][lr] = v1.z; As[lk+7][lr] = v1.w;
        }
        {
            const float* src = Wm + (size_t)(k0 + bk_r) * Esz + col0 + bc;
            float4 v0 = ((const float4*)src)[0];
            float4 v1 = ((const float4*)src)[1];
            *((float4*)&Bs[bk_r][bc])     = v0;
            *((float4*)&Bs[bk_r][bc + 4]) = v1;
        }
        __syncthreads();
        #pragma unroll
        for (int k = 0; k < BK; ++k) {
            float a8[8], b8[8];
            #pragma unroll
            for (int i = 0; i < 8; ++i) a8[i] = As[k][ty * 8 + i];
            #pragma unroll
            for (int j = 0; j < 8; ++j) b8[j] = Bs[k][tx * 8 + j];
            #pragma unroll
            for (int i = 0; i < 8; ++i)
                #pragma unroll
                for (int j = 0; j < 8; ++j)
                    acc[i][j] = fmaf(a8[i], b8[j], acc[i][j]);
        }
        __syncthreads();
    }

    #pragma unroll
    for (int i = 0; i < 8; ++i) {
        int row = row0 + ty * 8 + i;
        int b = row >> 12;       // row / 4096
        int s = row & 4095;
        #pragma unroll
        for (int j = 0; j < 8; ++j) {
            int n = col0 + tx * 8 + j;
            int h = n >> 6;
            int d = n & 63;
            float v = acc[i][j] + bias[n];
            v = fmaxf(v, 0.f) * scale;
            dst[(((size_t)b * Hh + h) * Ssz + s) * HDd + d] = v;
        }
    }
}

// ======================= Banded attention =======================
// One block per (b, h, 16-row group). Full 16x513 score band in LDS.
#define ROWS 16
#define KT 64
#define NKT 9       // covers keys s0-256 .. s0+319 (need up to s0+271)
#define LDKV 68     // padded stride (bank spread + float4 alignment)
#define LDQ 68

__global__ __launch_bounds__(256) void attn_kernel(
    const float* __restrict__ ws, const int* __restrict__ am,
    float* __restrict__ out_attn, float* __restrict__ out_probs)
{
    const float* Qp = ws;
    const float* Kp = ws + (size_t)Bsz * Hh * Ssz * HDd;
    const float* Vp = Kp + (size_t)Bsz * Hh * Ssz * HDd;

    __shared__ float qs[ROWS][LDQ];
    __shared__ float kv[KT][LDKV];
    __shared__ float sc[ROWS][NBAND];

    const int tid = threadIdx.x;
    const int ngrp = Ssz / ROWS;              // 256
    const int bh = blockIdx.x / ngrp;
    const int rg = blockIdx.x % ngrp;
    const int b = bh / Hh, h = bh % Hh;
    const int s0 = rg * ROWS;

    // init score band to "invalid"
    for (int i = tid; i < ROWS * NBAND; i += 256) (&sc[0][0])[i] = -1e9f;

    // stage q rows (already scaled by 1/8 in GEMM)
    {
        int xq = tid >> 4, d0 = (tid & 15) * 4;
        float4 qv = *(const float4*)(Qp + ((size_t)bh * Ssz + s0 + xq) * HDd + d0);
        *(float4*)&qs[xq][d0] = qv;
    }
    __syncthreads();

    const int x = tid >> 4;     // row 0..15 owned by this 16-lane group
    const int i16 = tid & 15;

    // cache my q row in registers
    float qreg[HDd];
    #pragma unroll
    for (int d = 0; d < HDd; ++d) qreg[d] = qs[x][d];

    // -------- Phase 1: band scores --------
    for (int kt = 0; kt < NKT; ++kt) {
        const int key0 = s0 - 256 + kt * 64;
        {   // stage K tile (zero-fill out of range)
            int j = tid >> 2;
            int d0 = (tid & 3) * 16;
            int key = key0 + j;
            float4 r0 = {0,0,0,0}, r1 = r0, r2 = r0, r3 = r0;
            if (key >= 0 && key < Ssz) {
                const float4* src = (const float4*)(Kp + ((size_t)bh * Ssz + key) * HDd + d0);
                r0 = src[0]; r1 = src[1]; r2 = src[2]; r3 = src[3];
            }
            float4* dstp = (float4*)&kv[j][d0];
            dstp[0] = r0; dstp[1] = r1; dstp[2] = r2; dstp[3] = r3;
        }
        __syncthreads();
        #pragma unroll
        for (int a = 0; a < 4; ++a) {
            int j = i16 + a * 16;
            int key = key0 + j;
            int y = kt * 64 + j - x;
            if (key >= 0 && key < Ssz && y >= 0 && y <= 2 * Ww) {
                float dot = 0.f;
                #pragma unroll
                for (int t = 0; t < 16; ++t) {
                    float4 kk = *(const float4*)&kv[j][t * 4];
                    dot = fmaf(qreg[t*4+0], kk.x, dot);
                    dot = fmaf(qreg[t*4+1], kk.y, dot);
                    dot = fmaf(qreg[t*4+2], kk.z, dot);
                    dot = fmaf(qreg[t*4+3], kk.w, dot);
                }
                float fmv = (am[b * Ssz + key] != 0) ? -10000.f : 0.f;
                sc[x][y] = dot + fmv;
            }
        }
        __syncthreads();
    }

    // -------- Phase 2: softmax + probs output --------
    {
        float m = -1e30f;
        for (int y = i16; y < NBAND; y += 16) m = fmaxf(m, sc[x][y]);
        m = fmaxf(m, __shfl_xor(m, 1));
        m = fmaxf(m, __shfl_xor(m, 2));
        m = fmaxf(m, __shfl_xor(m, 4));
        m = fmaxf(m, __shfl_xor(m, 8));
        float l = 0.f;
        for (int y = i16; y < NBAND; y += 16) {
            float e = __expf(sc[x][y] - m);   // -1e9 entries underflow to exactly 0
            sc[x][y] = e;
            l += e;
        }
        l += __shfl_xor(l, 1);
        l += __shfl_xor(l, 2);
        l += __shfl_xor(l, 4);
        l += __shfl_xor(l, 8);
        float rinv = 1.f / l;
        float* pbase = out_probs + ((size_t)(b * Ssz + s0 + x) * Hh + h) * NBAND;
        for (int y = i16; y < NBAND; y += 16) {
            float p = sc[x][y] * rinv;
            sc[x][y] = p;
            pbase[y] = p;
        }
    }
    __syncthreads();

    // -------- Phase 3: PV --------
    float4 acc = {0.f, 0.f, 0.f, 0.f};
    const int d0 = i16 * 4;     // each lane owns 4 contiguous d
    for (int kt = 0; kt < NKT; ++kt) {
        const int key0 = s0 - 256 + kt * 64;
        {   // stage V tile
            int j = tid >> 2;
            int dd = (tid & 3) * 16;
            int key = key0 + j;
            float4 r0 = {0,0,0,0}, r1 = r0, r2 = r0, r3 = r0;
            if (key >= 0 && key < Ssz) {
                const float4* src = (const float4*)(Vp + ((size_t)bh * Ssz + key) * HDd + dd);
                r0 = src[0]; r1 = src[1]; r2 = src[2]; r3 = src[3];
            }
            float4* dstp = (float4*)&kv[j][dd];
            dstp[0] = r0; dstp[1] = r1; dstp[2] = r2; dstp[3] = r3;
        }
        __syncthreads();
        for (int j = 0; j < KT; ++j) {
            int y = kt * 64 + j - x;
            if (y >= 0 && y <= 2 * Ww) {
                float p = sc[x][y];           // 0 for invalid keys
                float4 vv = *(const float4*)&kv[j][d0];
                acc.x = fmaf(p, vv.x, acc.x);
                acc.y = fmaf(p, vv.y, acc.y);
                acc.z = fmaf(p, vv.z, acc.z);
                acc.w = fmaf(p, vv.w, acc.w);
            }
        }
        __syncthreads();
    }
    {
        float* obase = out_attn + ((size_t)b * Ssz + s0 + x) * Esz + h * HDd;
        *(float4*)&obase[d0] = acc;
    }
}

// ======================= launch =======================
extern "C" void kernel_launch(void* const* d_in, const int* in_sizes, int n_in,
                              void* d_out, int out_size, void* d_ws, size_t ws_size,
                              hipStream_t stream)
{
    const float* hs = (const float*)d_in[0];
    const int*   am = (const int*)d_in[1];
    const float* Wq = (const float*)d_in[2];
    const float* bq = (const float*)d_in[3];
    const float* Wk = (const float*)d_in[4];
    const float* bk = (const float*)d_in[5];
    const float* Wv = (const float*)d_in[6];
    const float* bv = (const float*)d_in[7];

    float* ws = (float*)d_ws;                       // q,k,v head-major: 3 * 25.2 MB
    float* out_attn  = (float*)d_out;               // (B,S,E)
    float* out_probs = out_attn + (size_t)Bsz * Ssz * Esz;  // (B,S,H,513)

    dim3 g1(Esz / BN, (Bsz * Ssz) / BM, 3);         // (6, 64, 3)
    qkv_gemm<<<g1, 256, 0, stream>>>(hs, Wq, bq, Wk, bk, Wv, bv, ws);

    dim3 g2(Bsz * Hh * (Ssz / ROWS));               // 6144
    attn_kernel<<<g2, 256, 0, stream>>>(ws, am, out_attn, out_probs);
}

// Round 3
// 892.868 us; speedup vs baseline: 1.2753x; 1.2753x over previous
//
#include <hip/hip_runtime.h>
#include <hip/hip_bf16.h>
#include <math.h>

#define Bsz 2
#define Ssz 4096
#define Esz 768
#define Hh 12
#define HDd 64
#define Ww 256
#define NBAND 513   // 2*W+1

typedef __attribute__((ext_vector_type(8))) short    bf16x8;
typedef __attribute__((ext_vector_type(8))) unsigned short us8;
typedef __attribute__((ext_vector_type(4))) float    f32x4;

// ws layout (bytes):
//   [0)                WT_hi : 3*768*768 bf16  ([z][n][k], transposed W)
//   [3538944)          WT_lo : 3*768*768 bf16
//   [7077888)          qkv   : 3 * 8192*768 fp32  (head-major [z][b][h][s][d])
#define WT_ELEMS (3*768*768)
#define QKV_BYTE_OFF ((size_t)2 * WT_ELEMS * 2)

__device__ inline unsigned short f2bf(float x) {
    unsigned int u = __float_as_uint(x);
    return (unsigned short)((u + 0x7fffu + ((u >> 16) & 1u)) >> 16);
}

// ======================= W transpose + split-bf16 cast =======================
__global__ __launch_bounds__(256) void cast_wt(
    const float* __restrict__ W0, const float* __restrict__ W1, const float* __restrict__ W2,
    unsigned short* __restrict__ wt_hi, unsigned short* __restrict__ wt_lo)
{
    const int z = blockIdx.z;
    const float* Wm = (z == 0) ? W0 : (z == 1) ? W1 : W2;
    __shared__ float tile[32][33];
    const int t = threadIdx.x;
    const int k0 = blockIdx.x * 32, n0 = blockIdx.y * 32;
    {
        int r = t >> 3, c = (t & 7) * 4;
        float4 v = *(const float4*)(Wm + (size_t)(k0 + r) * Esz + n0 + c);
        tile[r][c] = v.x; tile[r][c+1] = v.y; tile[r][c+2] = v.z; tile[r][c+3] = v.w;
    }
    __syncthreads();
    {
        int nr = t >> 3, c = (t & 7) * 4;   // c = k offset within tile
        unsigned short hb[4], lb[4];
        #pragma unroll
        for (int i = 0; i < 4; ++i) {
            float x = tile[c + i][nr];
            unsigned short h = f2bf(x);
            float hf = __uint_as_float((unsigned int)h << 16);
            hb[i] = h;
            lb[i] = f2bf(x - hf);
        }
        size_t off = ((size_t)z * Esz + n0 + nr) * Esz + k0 + c;
        *(ushort4*)(wt_hi + off) = make_ushort4(hb[0], hb[1], hb[2], hb[3]);
        *(ushort4*)(wt_lo + off) = make_ushort4(lb[0], lb[1], lb[2], lb[3]);
    }
}

// ======================= QKV GEMM (split-bf16 MFMA) =======================
// C = relu(A @ W + b) * scale, head-major out. A fp32 (converted in-kernel),
// W pre-transposed/cast. 128x128 tile, BK=32, 4 waves (2x2), 16x16x32 MFMA.
#define BMg 128
#define BNg 128
#define BKg 32
#define LDT 40   // LDS row stride in bf16 elems (80 B: 16B-aligned, spreads banks)

__global__ __launch_bounds__(256) void qkv_gemm_mfma(
    const float* __restrict__ A,
    const unsigned short* __restrict__ wt_hi, const unsigned short* __restrict__ wt_lo,
    const float* __restrict__ b0, const float* __restrict__ b1, const float* __restrict__ b2,
    float* __restrict__ qkv)
{
    const int z = blockIdx.z;
    const float* bias = (z == 0) ? b0 : (z == 1) ? b1 : b2;
    const float scale = (z == 0) ? 0.125f : 1.0f;
    float* dst = qkv + (size_t)z * Bsz * Hh * Ssz * HDd;

    __shared__ unsigned short Ah[BMg][LDT], Al[BMg][LDT];
    __shared__ unsigned short Bh[BNg][LDT], Bl[BNg][LDT];

    const int t = threadIdx.x;
    const int row0 = blockIdx.y * BMg;
    const int col0 = blockIdx.x * BNg;
    const int wv = t >> 6, ln = t & 63;
    const int wm = wv >> 1, wn = wv & 1;
    const int fr = ln & 15, fc = ln >> 4;

    f32x4 acc[4][4] = {};

    const int sr = t >> 1;            // 0..127: A row / WT row (=output col)
    const int sk = (t & 1) * 16;      // k offset 0/16

    const float* arow = A + (size_t)(row0 + sr) * Esz;
    const unsigned short* wth = wt_hi + ((size_t)z * Esz + col0 + sr) * Esz;
    const unsigned short* wtl = wt_lo + ((size_t)z * Esz + col0 + sr) * Esz;

    for (int k0 = 0; k0 < Esz; k0 += BKg) {
        // ---- stage A (fp32 -> hi/lo bf16) ----
        {
            float4 v0 = *(const float4*)(arow + k0 + sk);
            float4 v1 = *(const float4*)(arow + k0 + sk + 4);
            float4 v2 = *(const float4*)(arow + k0 + sk + 8);
            float4 v3 = *(const float4*)(arow + k0 + sk + 12);
            float f[16] = {v0.x,v0.y,v0.z,v0.w, v1.x,v1.y,v1.z,v1.w,
                           v2.x,v2.y,v2.z,v2.w, v3.x,v3.y,v3.z,v3.w};
            us8 h0, h1, l0, l1;
            #pragma unroll
            for (int i = 0; i < 8; ++i) {
                unsigned short hb = f2bf(f[i]);
                h0[i] = hb;
                l0[i] = f2bf(f[i] - __uint_as_float((unsigned int)hb << 16));
            }
            #pragma unroll
            for (int i = 0; i < 8; ++i) {
                unsigned short hb = f2bf(f[8 + i]);
                h1[i] = hb;
                l1[i] = f2bf(f[8 + i] - __uint_as_float((unsigned int)hb << 16));
            }
            *(us8*)&Ah[sr][sk]     = h0;
            *(us8*)&Ah[sr][sk + 8] = h1;
            *(us8*)&Al[sr][sk]     = l0;
            *(us8*)&Al[sr][sk + 8] = l1;
        }
        // ---- stage B (pre-cast bf16 copy) ----
        {
            *(us8*)&Bh[sr][sk]     = *(const us8*)(wth + k0 + sk);
            *(us8*)&Bh[sr][sk + 8] = *(const us8*)(wth + k0 + sk + 8);
            *(us8*)&Bl[sr][sk]     = *(const us8*)(wtl + k0 + sk);
            *(us8*)&Bl[sr][sk + 8] = *(const us8*)(wtl + k0 + sk + 8);
        }
        __syncthreads();

        bf16x8 ah[4], al[4], bh[4], bl[4];
        #pragma unroll
        for (int m = 0; m < 4; ++m) {
            ah[m] = *(const bf16x8*)&Ah[wm * 64 + m * 16 + fr][fc * 8];
            al[m] = *(const bf16x8*)&Al[wm * 64 + m * 16 + fr][fc * 8];
        }
        #pragma unroll
        for (int n = 0; n < 4; ++n) {
            bh[n] = *(const bf16x8*)&Bh[wn * 64 + n * 16 + fr][fc * 8];
            bl[n] = *(const bf16x8*)&Bl[wn * 64 + n * 16 + fr][fc * 8];
        }
        #pragma unroll
        for (int m = 0; m < 4; ++m)
            #pragma unroll
            for (int n = 0; n < 4; ++n) {
                acc[m][n] = __builtin_amdgcn_mfma_f32_16x16x32_bf16(ah[m], bh[n], acc[m][n], 0, 0, 0);
                acc[m][n] = __builtin_amdgcn_mfma_f32_16x16x32_bf16(ah[m], bl[n], acc[m][n], 0, 0, 0);
                acc[m][n] = __builtin_amdgcn_mfma_f32_16x16x32_bf16(al[m], bh[n], acc[m][n], 0, 0, 0);
            }
        __syncthreads();
    }

    // ---- epilogue: bias + relu + scale, head-major scatter ----
    #pragma unroll
    for (int n = 0; n < 4; ++n) {
        int col = col0 + wn * 64 + n * 16 + fr;
        int h = col >> 6, d = col & 63;
        float bv = bias[col];
        #pragma unroll
        for (int m = 0; m < 4; ++m) {
            int rowb = row0 + wm * 64 + m * 16 + fc * 4;
            #pragma unroll
            for (int r = 0; r < 4; ++r) {
                int row = rowb + r;
                int b = row >> 12, s = row & 4095;
                float v = fmaxf(acc[m][n][r] + bv, 0.f) * scale;
                dst[(((size_t)b * Hh + h) * Ssz + s) * HDd + d] = v;
            }
        }
    }
}

// ======================= Banded attention (unchanged from R1) =======================
#define ROWS 16
#define KT 64
#define NKT 9
#define LDKV 68
#define LDQ 68

__global__ __launch_bounds__(256) void attn_kernel(
    const float* __restrict__ ws, const int* __restrict__ am,
    float* __restrict__ out_attn, float* __restrict__ out_probs)
{
    const float* Qp = ws;
    const float* Kp = ws + (size_t)Bsz * Hh * Ssz * HDd;
    const float* Vp = Kp + (size_t)Bsz * Hh * Ssz * HDd;

    __shared__ float qs[ROWS][LDQ];
    __shared__ float kv[KT][LDKV];
    __shared__ float sc[ROWS][NBAND];

    const int tid = threadIdx.x;
    const int ngrp = Ssz / ROWS;
    const int bh = blockIdx.x / ngrp;
    const int rg = blockIdx.x % ngrp;
    const int b = bh / Hh, h = bh % Hh;
    const int s0 = rg * ROWS;

    for (int i = tid; i < ROWS * NBAND; i += 256) (&sc[0][0])[i] = -1e9f;

    {
        int xq = tid >> 4, d0 = (tid & 15) * 4;
        float4 qv = *(const float4*)(Qp + ((size_t)bh * Ssz + s0 + xq) * HDd + d0);
        *(float4*)&qs[xq][d0] = qv;
    }
    __syncthreads();

    const int x = tid >> 4;
    const int i16 = tid & 15;

    float qreg[HDd];
    #pragma unroll
    for (int d = 0; d < HDd; ++d) qreg[d] = qs[x][d];

    for (int kt = 0; kt < NKT; ++kt) {
        const int key0 = s0 - 256 + kt * 64;
        {
            int j = tid >> 2;
            int d0 = (tid & 3) * 16;
            int key = key0 + j;
            float4 r0 = {0,0,0,0}, r1 = r0, r2 = r0, r3 = r0;
            if (key >= 0 && key < Ssz) {
                const float4* src = (const float4*)(Kp + ((size_t)bh * Ssz + key) * HDd + d0);
                r0 = src[0]; r1 = src[1]; r2 = src[2]; r3 = src[3];
            }
            float4* dstp = (float4*)&kv[j][d0];
            dstp[0] = r0; dstp[1] = r1; dstp[2] = r2; dstp[3] = r3;
        }
        __syncthreads();
        #pragma unroll
        for (int a = 0; a < 4; ++a) {
            int j = i16 + a * 16;
            int key = key0 + j;
            int y = kt * 64 + j - x;
            if (key >= 0 && key < Ssz && y >= 0 && y <= 2 * Ww) {
                float dot = 0.f;
                #pragma unroll
                for (int t = 0; t < 16; ++t) {
                    float4 kk = *(const float4*)&kv[j][t * 4];
                    dot = fmaf(qreg[t*4+0], kk.x, dot);
                    dot = fmaf(qreg[t*4+1], kk.y, dot);
                    dot = fmaf(qreg[t*4+2], kk.z, dot);
                    dot = fmaf(qreg[t*4+3], kk.w, dot);
                }
                float fmv = (am[b * Ssz + key] != 0) ? -10000.f : 0.f;
                sc[x][y] = dot + fmv;
            }
        }
        __syncthreads();
    }

    {
        float m = -1e30f;
        for (int y = i16; y < NBAND; y += 16) m = fmaxf(m, sc[x][y]);
        m = fmaxf(m, __shfl_xor(m, 1));
        m = fmaxf(m, __shfl_xor(m, 2));
        m = fmaxf(m, __shfl_xor(m, 4));
        m = fmaxf(m, __shfl_xor(m, 8));
        float l = 0.f;
        for (int y = i16; y < NBAND; y += 16) {
            float e = __expf(sc[x][y] - m);
            sc[x][y] = e;
            l += e;
        }
        l += __shfl_xor(l, 1);
        l += __shfl_xor(l, 2);
        l += __shfl_xor(l, 4);
        l += __shfl_xor(l, 8);
        float rinv = 1.f / l;
        float* pbase = out_probs + ((size_t)(b * Ssz + s0 + x) * Hh + h) * NBAND;
        for (int y = i16; y < NBAND; y += 16) {
            float p = sc[x][y] * rinv;
            sc[x][y] = p;
            pbase[y] = p;
        }
    }
    __syncthreads();

    float4 acc = {0.f, 0.f, 0.f, 0.f};
    const int d0 = i16 * 4;
    for (int kt = 0; kt < NKT; ++kt) {
        const int key0 = s0 - 256 + kt * 64;
        {
            int j = tid >> 2;
            int dd = (tid & 3) * 16;
            int key = key0 + j;
            float4 r0 = {0,0,0,0}, r1 = r0, r2 = r0, r3 = r0;
            if (key >= 0 && key < Ssz) {
                const float4* src = (const float4*)(Vp + ((size_t)bh * Ssz + key) * HDd + dd);
                r0 = src[0]; r1 = src[1]; r2 = src[2]; r3 = src[3];
            }
            float4* dstp = (float4*)&kv[j][dd];
            dstp[0] = r0; dstp[1] = r1; dstp[2] = r2; dstp[3] = r3;
        }
        __syncthreads();
        for (int j = 0; j < KT; ++j) {
            int y = kt * 64 + j - x;
            if (y >= 0 && y <= 2 * Ww) {
                float p = sc[x][y];
                float4 vv = *(const float4*)&kv[j][d0];
                acc.x = fmaf(p, vv.x, acc.x);
                acc.y = fmaf(p, vv.y, acc.y);
                acc.z = fmaf(p, vv.z, acc.z);
                acc.w = fmaf(p, vv.w, acc.w);
            }
        }
        __syncthreads();
    }
    {
        float* obase = out_attn + ((size_t)b * Ssz + s0 + x) * Esz + h * HDd;
        *(float4*)&obase[d0] = acc;
    }
}

// ======================= launch =======================
extern "C" void kernel_launch(void* const* d_in, const int* in_sizes, int n_in,
                              void* d_out, int out_size, void* d_ws, size_t ws_size,
                              hipStream_t stream)
{
    const float* hs = (const float*)d_in[0];
    const int*   am = (const int*)d_in[1];
    const float* Wq = (const float*)d_in[2];
    const float* bq = (const float*)d_in[3];
    const float* Wk = (const float*)d_in[4];
    const float* bk = (const float*)d_in[5];
    const float* Wv = (const float*)d_in[6];
    const float* bv = (const float*)d_in[7];

    unsigned short* wt_hi = (unsigned short*)d_ws;
    unsigned short* wt_lo = wt_hi + WT_ELEMS;
    float* qkv = (float*)((char*)d_ws + QKV_BYTE_OFF);

    float* out_attn  = (float*)d_out;
    float* out_probs = out_attn + (size_t)Bsz * Ssz * Esz;

    dim3 gc(24, 24, 3);
    cast_wt<<<gc, 256, 0, stream>>>(Wq, Wk, Wv, wt_hi, wt_lo);

    dim3 gg(Esz / BNg, (Bsz * Ssz) / BMg, 3);   // (6, 64, 3)
    qkv_gemm_mfma<<<gg, 256, 0, stream>>>(hs, wt_hi, wt_lo, bq, bk, bv, qkv);

    dim3 g2(Bsz * Hh * (Ssz / ROWS));           // 6144
    attn_kernel<<<g2, 256, 0, stream>>>(qkv, am, out_attn, out_probs);
}

// Round 4
// 724.507 us; speedup vs baseline: 1.5716x; 1.2324x over previous
//
#include <hip/hip_runtime.h>
#include <hip/hip_bf16.h>
#include <math.h>

#define Bsz 2
#define Ssz 4096
#define Esz 768
#define Hh 12
#define HDd 64
#define Ww 256
#define NBAND 513   // 2*W+1
#define BH (Bsz*Hh) // 24

typedef __attribute__((ext_vector_type(8))) short    bf16x8;
typedef __attribute__((ext_vector_type(8))) unsigned short us8;
typedef __attribute__((ext_vector_type(4))) float    f32x4;

// ws layout (u16 units):
//   wt_hi  : 3*768*768
//   wt_lo  : 3*768*768
//   qh,ql,kh,kl,vh,vl : each BH*4096*64   (row-major [bh][s][d], split bf16)
//   vth,vtl           : each BH*64*4096   ([bh][d][s], split bf16)
#define WT_ELEMS (3*768*768)
#define QKV_ELEMS ((size_t)BH * Ssz * HDd)

__device__ inline unsigned short f2bf(float x) {
    unsigned int u = __float_as_uint(x);
    return (unsigned short)((u + 0x7fffu + ((u >> 16) & 1u)) >> 16);
}
__device__ inline float bf2f(unsigned short h) {
    return __uint_as_float((unsigned int)h << 16);
}

// ======================= W transpose + split-bf16 cast =======================
__global__ __launch_bounds__(256) void cast_wt(
    const float* __restrict__ W0, const float* __restrict__ W1, const float* __restrict__ W2,
    unsigned short* __restrict__ wt_hi, unsigned short* __restrict__ wt_lo)
{
    const int z = blockIdx.z;
    const float* Wm = (z == 0) ? W0 : (z == 1) ? W1 : W2;
    __shared__ float tile[32][33];
    const int t = threadIdx.x;
    const int k0 = blockIdx.x * 32, n0 = blockIdx.y * 32;
    {
        int r = t >> 3, c = (t & 7) * 4;
        float4 v = *(const float4*)(Wm + (size_t)(k0 + r) * Esz + n0 + c);
        tile[r][c] = v.x; tile[r][c+1] = v.y; tile[r][c+2] = v.z; tile[r][c+3] = v.w;
    }
    __syncthreads();
    {
        int nr = t >> 3, c = (t & 7) * 4;
        unsigned short hb[4], lb[4];
        #pragma unroll
        for (int i = 0; i < 4; ++i) {
            float x = tile[c + i][nr];
            unsigned short h = f2bf(x);
            hb[i] = h;
            lb[i] = f2bf(x - bf2f(h));
        }
        size_t off = ((size_t)z * Esz + n0 + nr) * Esz + k0 + c;
        *(ushort4*)(wt_hi + off) = make_ushort4(hb[0], hb[1], hb[2], hb[3]);
        *(ushort4*)(wt_lo + off) = make_ushort4(lb[0], lb[1], lb[2], lb[3]);
    }
}

// ======================= QKV GEMM (split-bf16 MFMA) =======================
// out: hi/lo bf16, head-major [z][bh][s][d]
#define BMg 128
#define BNg 128
#define BKg 32
#define LDT 40

__global__ __launch_bounds__(256) void qkv_gemm_mfma(
    const float* __restrict__ A,
    const unsigned short* __restrict__ wt_hi, const unsigned short* __restrict__ wt_lo,
    const float* __restrict__ b0, const float* __restrict__ b1, const float* __restrict__ b2,
    unsigned short* __restrict__ qkvb)
{
    const int z = blockIdx.z;
    const float* bias = (z == 0) ? b0 : (z == 1) ? b1 : b2;
    const float scale = (z == 0) ? 0.125f : 1.0f;
    unsigned short* zh = qkvb + (size_t)z * 2 * QKV_ELEMS;
    unsigned short* zl = zh + QKV_ELEMS;

    __shared__ unsigned short Ah[BMg][LDT], Al[BMg][LDT];
    __shared__ unsigned short Bh[BNg][LDT], Bl[BNg][LDT];

    const int t = threadIdx.x;
    const int row0 = blockIdx.y * BMg;
    const int col0 = blockIdx.x * BNg;
    const int wv = t >> 6, ln = t & 63;
    const int wm = wv >> 1, wn = wv & 1;
    const int fr = ln & 15, fc = ln >> 4;

    f32x4 acc[4][4] = {};

    const int sr = t >> 1;
    const int sk = (t & 1) * 16;

    const float* arow = A + (size_t)(row0 + sr) * Esz;
    const unsigned short* wth = wt_hi + ((size_t)z * Esz + col0 + sr) * Esz;
    const unsigned short* wtl = wt_lo + ((size_t)z * Esz + col0 + sr) * Esz;

    for (int k0 = 0; k0 < Esz; k0 += BKg) {
        {
            float4 v0 = *(const float4*)(arow + k0 + sk);
            float4 v1 = *(const float4*)(arow + k0 + sk + 4);
            float4 v2 = *(const float4*)(arow + k0 + sk + 8);
            float4 v3 = *(const float4*)(arow + k0 + sk + 12);
            float f[16] = {v0.x,v0.y,v0.z,v0.w, v1.x,v1.y,v1.z,v1.w,
                           v2.x,v2.y,v2.z,v2.w, v3.x,v3.y,v3.z,v3.w};
            us8 h0, h1, l0, l1;
            #pragma unroll
            for (int i = 0; i < 8; ++i) {
                unsigned short hb = f2bf(f[i]);
                h0[i] = hb;
                l0[i] = f2bf(f[i] - bf2f(hb));
            }
            #pragma unroll
            for (int i = 0; i < 8; ++i) {
                unsigned short hb = f2bf(f[8 + i]);
                h1[i] = hb;
                l1[i] = f2bf(f[8 + i] - bf2f(hb));
            }
            *(us8*)&Ah[sr][sk]     = h0;
            *(us8*)&Ah[sr][sk + 8] = h1;
            *(us8*)&Al[sr][sk]     = l0;
            *(us8*)&Al[sr][sk + 8] = l1;
        }
        {
            *(us8*)&Bh[sr][sk]     = *(const us8*)(wth + k0 + sk);
            *(us8*)&Bh[sr][sk + 8] = *(const us8*)(wth + k0 + sk + 8);
            *(us8*)&Bl[sr][sk]     = *(const us8*)(wtl + k0 + sk);
            *(us8*)&Bl[sr][sk + 8] = *(const us8*)(wtl + k0 + sk + 8);
        }
        __syncthreads();

        bf16x8 ah[4], al[4], bh[4], bl[4];
        #pragma unroll
        for (int m = 0; m < 4; ++m) {
            ah[m] = *(const bf16x8*)&Ah[wm * 64 + m * 16 + fr][fc * 8];
            al[m] = *(const bf16x8*)&Al[wm * 64 + m * 16 + fr][fc * 8];
        }
        #pragma unroll
        for (int n = 0; n < 4; ++n) {
            bh[n] = *(const bf16x8*)&Bh[wn * 64 + n * 16 + fr][fc * 8];
            bl[n] = *(const bf16x8*)&Bl[wn * 64 + n * 16 + fr][fc * 8];
        }
        #pragma unroll
        for (int m = 0; m < 4; ++m)
            #pragma unroll
            for (int n = 0; n < 4; ++n) {
                acc[m][n] = __builtin_amdgcn_mfma_f32_16x16x32_bf16(ah[m], bh[n], acc[m][n], 0, 0, 0);
                acc[m][n] = __builtin_amdgcn_mfma_f32_16x16x32_bf16(ah[m], bl[n], acc[m][n], 0, 0, 0);
                acc[m][n] = __builtin_amdgcn_mfma_f32_16x16x32_bf16(al[m], bh[n], acc[m][n], 0, 0, 0);
            }
        __syncthreads();
    }

    #pragma unroll
    for (int n = 0; n < 4; ++n) {
        int col = col0 + wn * 64 + n * 16 + fr;
        int h = col >> 6, d = col & 63;
        float bv = bias[col];
        #pragma unroll
        for (int m = 0; m < 4; ++m) {
            int rowb = row0 + wm * 64 + m * 16 + fc * 4;
            #pragma unroll
            for (int r = 0; r < 4; ++r) {
                int row = rowb + r;
                int b = row >> 12, s = row & 4095;
                float v = fmaxf(acc[m][n][r] + bv, 0.f) * scale;
                unsigned short hv = f2bf(v);
                unsigned short lv = f2bf(v - bf2f(hv));
                size_t idx = (((size_t)b * Hh + h) * Ssz + s) * HDd + d;
                zh[idx] = hv;
                zl[idx] = lv;
            }
        }
    }
}

// ======================= V transpose (bf16 hi/lo -> [bh][d][s]) =======================
__global__ __launch_bounds__(256) void transpose_v(
    const unsigned short* __restrict__ vh, const unsigned short* __restrict__ vl,
    unsigned short* __restrict__ vth, unsigned short* __restrict__ vtl)
{
    __shared__ unsigned short tile[64][72];
    const int z = blockIdx.z;
    const unsigned short* src = z ? vl : vh;
    unsigned short*       dst = z ? vtl : vth;
    const int bh = blockIdx.y;
    const int st = blockIdx.x;          // 64-row s-tile
    const int t = threadIdx.x;
    {
        int sr = t >> 2, dc = (t & 3) * 16;
        const unsigned short* sp = src + ((size_t)bh * Ssz + st * 64 + sr) * HDd + dc;
        *(us8*)&tile[sr][dc]     = *(const us8*)sp;
        *(us8*)&tile[sr][dc + 8] = *(const us8*)(sp + 8);
    }
    __syncthreads();
    {
        int dr = t >> 2, sc = (t & 3) * 16;
        us8 b0, b1;
        #pragma unroll
        for (int j = 0; j < 8; ++j) b0[j] = tile[sc + j][dr];
        #pragma unroll
        for (int j = 0; j < 8; ++j) b1[j] = tile[sc + 8 + j][dr];
        unsigned short* dp = dst + ((size_t)bh * HDd + dr) * Ssz + st * 64 + sc;
        *(us8*)dp       = b0;
        *(us8*)(dp + 8) = b1;
    }
}

// ======================= MFMA banded attention =======================
// One wave (64-thr block) per (bh, 16 q-rows). S band = 33 tiles of 16x16 in VGPRs.
__global__ __launch_bounds__(64) void attn_mfma(
    const unsigned short* __restrict__ Qh, const unsigned short* __restrict__ Ql,
    const unsigned short* __restrict__ Kh, const unsigned short* __restrict__ Kl,
    const unsigned short* __restrict__ Vth, const unsigned short* __restrict__ Vtl,
    const int* __restrict__ am,
    float* __restrict__ out_attn, float* __restrict__ out_probs)
{
    __shared__ unsigned short Ph[16][32], Pl[16][32];

    const int blk = blockIdx.x;
    const int qg = blk & 255;            // 4096/16 groups
    const int bh = blk >> 8;             // 0..23
    const int b = bh / Hh, h = bh % Hh;
    const int s0w = qg * 16;
    const int ln = threadIdx.x;
    const int col = ln & 15;
    const int grp = ln >> 4;

    // ---- Q fragments (A-operand: row=lane&15, k=(lane>>4)*8+j) ----
    const size_t qbase = ((size_t)bh * Ssz + s0w + col) * HDd + grp * 8;
    const bf16x8 q_h0 = *(const bf16x8*)(Qh + qbase);
    const bf16x8 q_h1 = *(const bf16x8*)(Qh + qbase + 32);
    const bf16x8 q_l0 = *(const bf16x8*)(Ql + qbase);
    const bf16x8 q_l1 = *(const bf16x8*)(Ql + qbase + 32);

    // ---- Phase 1: scores, 33 key-tiles, split-bf16 3-product ----
    f32x4 sS[33];
    const int key0base = s0w - 256;
    #pragma unroll
    for (int t = 0; t < 33; ++t) {
        int key = key0base + 16 * t + col;
        int keyc = min(max(key, 0), Ssz - 1);
        const size_t kb = ((size_t)bh * Ssz + keyc) * HDd + grp * 8;
        bf16x8 k_h0 = *(const bf16x8*)(Kh + kb);
        bf16x8 k_h1 = *(const bf16x8*)(Kh + kb + 32);
        bf16x8 k_l0 = *(const bf16x8*)(Kl + kb);
        bf16x8 k_l1 = *(const bf16x8*)(Kl + kb + 32);
        f32x4 s = {};
        s = __builtin_amdgcn_mfma_f32_16x16x32_bf16(q_h0, k_h0, s, 0, 0, 0);
        s = __builtin_amdgcn_mfma_f32_16x16x32_bf16(q_h1, k_h1, s, 0, 0, 0);
        s = __builtin_amdgcn_mfma_f32_16x16x32_bf16(q_h0, k_l0, s, 0, 0, 0);
        s = __builtin_amdgcn_mfma_f32_16x16x32_bf16(q_h1, k_l1, s, 0, 0, 0);
        s = __builtin_amdgcn_mfma_f32_16x16x32_bf16(q_l0, k_h0, s, 0, 0, 0);
        s = __builtin_amdgcn_mfma_f32_16x16x32_bf16(q_l1, k_h1, s, 0, 0, 0);
        float fm = (am[b * Ssz + keyc] != 0) ? -10000.f : 0.f;
        bool keyok = (key >= 0) && (key < Ssz);
        #pragma unroll
        for (int r = 0; r < 4; ++r) {
            int x = grp * 4 + r;                 // q-row (D: row=(lane>>4)*4+r)
            int yy = 16 * t + col - x;           // band position 0..512
            bool valid = keyok && (yy >= 0) && (yy <= 512);
            s[r] = valid ? (s[r] + fm) : -1e9f;
        }
        sS[t] = s;
    }

    // ---- Phase 2: exact softmax (full row in regs) ----
    float mrow[4], lrow[4];
    #pragma unroll
    for (int r = 0; r < 4; ++r) {
        float m = sS[0][r];
        #pragma unroll
        for (int t = 1; t < 33; ++t) m = fmaxf(m, sS[t][r]);
        m = fmaxf(m, __shfl_xor(m, 1));
        m = fmaxf(m, __shfl_xor(m, 2));
        m = fmaxf(m, __shfl_xor(m, 4));
        m = fmaxf(m, __shfl_xor(m, 8));
        mrow[r] = m;
    }
    #pragma unroll
    for (int t = 0; t < 33; ++t)
        #pragma unroll
        for (int r = 0; r < 4; ++r)
            sS[t][r] = __expf(sS[t][r] - mrow[r]);
    #pragma unroll
    for (int r = 0; r < 4; ++r) {
        float l = 0.f;
        #pragma unroll
        for (int t = 0; t < 33; ++t) l += sS[t][r];
        l += __shfl_xor(l, 1);
        l += __shfl_xor(l, 2);
        l += __shfl_xor(l, 4);
        l += __shfl_xor(l, 8);
        lrow[r] = 1.f / l;
    }

    // ---- Phase 3: normalize + probs out ----
    #pragma unroll
    for (int t = 0; t < 33; ++t) {
        #pragma unroll
        for (int r = 0; r < 4; ++r) {
            float p = sS[t][r] * lrow[r];
            sS[t][r] = p;
            int x = grp * 4 + r;
            int yy = 16 * t + col - x;
            if (yy >= 0 && yy <= 512) {
                out_probs[(((size_t)b * Ssz + s0w + x) * Hh + h) * NBAND + yy] = p;
            }
        }
    }

    // ---- Phase 4: PV, key-tile pairs (k=32), P hi/lo via LDS transpose ----
    f32x4 acc[4] = {};
    #pragma unroll
    for (int pp = 0; pp < 17; ++pp) {
        __syncthreads();   // guard previous pair's frag reads
        #pragma unroll
        for (int tt = 0; tt < 2; ++tt) {
            const int t = 2 * pp + tt;
            if (t < 33) {
                #pragma unroll
                for (int r = 0; r < 4; ++r) {
                    float p = sS[t][r];
                    unsigned short hp = f2bf(p);
                    unsigned short lp = f2bf(p - bf2f(hp));
                    Ph[grp * 4 + r][tt * 16 + col] = hp;
                    Pl[grp * 4 + r][tt * 16 + col] = lp;
                }
            } else {
                #pragma unroll
                for (int r = 0; r < 4; ++r) {
                    Ph[grp * 4 + r][tt * 16 + col] = 0;
                    Pl[grp * 4 + r][tt * 16 + col] = 0;
                }
            }
        }
        __syncthreads();
        bf16x8 pah = *(const bf16x8*)&Ph[col][grp * 8];
        bf16x8 pal = *(const bf16x8*)&Pl[col][grp * 8];
        int kbase = s0w - 256 + 32 * pp + grp * 8;
        int kc = min(max(kbase, 0), Ssz - 8);
        #pragma unroll
        for (int dt = 0; dt < 4; ++dt) {
            const size_t vb = ((size_t)bh * HDd + dt * 16 + col) * Ssz + kc;
            bf16x8 v_h = *(const bf16x8*)(Vth + vb);
            bf16x8 v_l = *(const bf16x8*)(Vtl + vb);
            acc[dt] = __builtin_amdgcn_mfma_f32_16x16x32_bf16(pah, v_h, acc[dt], 0, 0, 0);
            acc[dt] = __builtin_amdgcn_mfma_f32_16x16x32_bf16(pah, v_l, acc[dt], 0, 0, 0);
            acc[dt] = __builtin_amdgcn_mfma_f32_16x16x32_bf16(pal, v_h, acc[dt], 0, 0, 0);
        }
    }

    // ---- Phase 5: attn out ----
    #pragma unroll
    for (int dt = 0; dt < 4; ++dt) {
        #pragma unroll
        for (int r = 0; r < 4; ++r) {
            int x = grp * 4 + r;
            int d = dt * 16 + col;
            out_attn[((size_t)b * Ssz + s0w + x) * Esz + h * HDd + d] = acc[dt][r];
        }
    }
}

// ======================= launch =======================
extern "C" void kernel_launch(void* const* d_in, const int* in_sizes, int n_in,
                              void* d_out, int out_size, void* d_ws, size_t ws_size,
                              hipStream_t stream)
{
    const float* hs = (const float*)d_in[0];
    const int*   am = (const int*)d_in[1];
    const float* Wq = (const float*)d_in[2];
    const float* bq = (const float*)d_in[3];
    const float* Wk = (const float*)d_in[4];
    const float* bk = (const float*)d_in[5];
    const float* Wv = (const float*)d_in[6];
    const float* bv = (const float*)d_in[7];

    unsigned short* wt_hi = (unsigned short*)d_ws;
    unsigned short* wt_lo = wt_hi + WT_ELEMS;
    unsigned short* qkvb  = wt_lo + WT_ELEMS;
    unsigned short* qh  = qkvb;
    unsigned short* ql  = qh + QKV_ELEMS;
    unsigned short* kh  = ql + QKV_ELEMS;
    unsigned short* kl  = kh + QKV_ELEMS;
    unsigned short* vh  = kl + QKV_ELEMS;
    unsigned short* vl  = vh + QKV_ELEMS;
    unsigned short* vth = vl + QKV_ELEMS;
    unsigned short* vtl = vth + QKV_ELEMS;

    float* out_attn  = (float*)d_out;
    float* out_probs = out_attn + (size_t)Bsz * Ssz * Esz;

    dim3 gc(24, 24, 3);
    cast_wt<<<gc, 256, 0, stream>>>(Wq, Wk, Wv, wt_hi, wt_lo);

    dim3 gg(Esz / BNg, (Bsz * Ssz) / BMg, 3);
    qkv_gemm_mfma<<<gg, 256, 0, stream>>>(hs, wt_hi, wt_lo, bq, bk, bv, qkvb);

    dim3 gt(Ssz / 64, BH, 2);
    transpose_v<<<gt, 256, 0, stream>>>(vh, vl, vth, vtl);

    dim3 ga(BH * (Ssz / 16));   // 6144 one-wave blocks
    attn_mfma<<<ga, 64, 0, stream>>>(qh, ql, kh, kl, vth, vtl, am, out_attn, out_probs);
}